// Round 13
// baseline (189.569 us; speedup 1.0000x reference)
//
#include <hip/hip_runtime.h>
#include <cstddef>
#include <cstdint>

// Problem constants (match reference)
#define BATCH 2
#define SEQ 8192
#define CH 256
#define NLM 40
#define NLMP 48               // landmark rows padded to 3 MFMA N-tiles
#define MROWS (BATCH * SEQ)   // 16384
#define INV_SCALE 0.0625f     // 1/sqrt(256)
#define NCBLK 256             // convert_colsum blocks per batch (SEQ/32)

typedef unsigned short ushort_t;
typedef __attribute__((ext_vector_type(8))) short short8;    // 8 bf16 (4 VGPRs)
typedef __attribute__((ext_vector_type(4))) float floatx4;   // MFMA acc

// round-to-nearest-even fp32 -> bf16
__device__ __forceinline__ ushort_t f2bf(float f) {
    unsigned int u = __float_as_uint(f);
    u += 0x7FFFu + ((u >> 16) & 1u);
    return (ushort_t)(u >> 16);
}
__device__ __forceinline__ float bf2f(ushort_t u) {
    return __uint_as_float(((unsigned)u) << 16);
}

// async global->LDS, 16B per lane. LDS dest = wave-uniform base + lane*16
// (m104); global src is per-lane. Drained by __syncthreads (vmcnt0 before
// barrier).
__device__ __forceinline__ void gload_lds16(const ushort_t* g, ushort_t* l) {
    __builtin_amdgcn_global_load_lds(
        (const __attribute__((address_space(1))) unsigned int*)g,
        (__attribute__((address_space(3))) unsigned int*)l, 16, 0, 0);
}

// ---------------------------------------------------------------------------
// convert_colsum: xbf = bf16(x); partial[b][blk][c] = sum of 32 rows of col c.
// grid (SEQ/32, B) = 512 blocks, block 256.
// ---------------------------------------------------------------------------
__global__ __launch_bounds__(256) void convert_colsum(const float* __restrict__ x,
                                                      ushort_t* __restrict__ xbf,
                                                      float* __restrict__ partial) {
    __shared__ float red[4][256];
    const int b = blockIdx.y;
    const int r0 = blockIdx.x * 32;
    const int t = threadIdx.x;
    const int c4 = (t & 63) * 4;     // 0..252
    const int rg = t >> 6;           // 0..3
    const float* base = x + ((size_t)b * SEQ + r0) * 256;
    ushort_t* obase = xbf + ((size_t)b * SEQ + r0) * 256;
    float4 s = {0.f, 0.f, 0.f, 0.f};
#pragma unroll
    for (int i = 0; i < 8; i++) {
        const int r = rg + i * 4;    // 0..31
        const float4 a = *(const float4*)&base[(size_t)r * 256 + c4];
        uint2 o;
        o.x = f2bf(a.x) | ((unsigned)f2bf(a.y) << 16);
        o.y = f2bf(a.z) | ((unsigned)f2bf(a.w) << 16);
        *(uint2*)&obase[(size_t)r * 256 + c4] = o;
        s.x += a.x; s.y += a.y; s.z += a.z; s.w += a.w;
    }
    *(float4*)&red[rg][c4] = s;
    __syncthreads();
    const float tot = red[0][t] + red[1][t] + red[2][t] + red[3][t];
    partial[((size_t)b * NCBLK + blockIdx.x) * 256 + t] = tot;
}

// ---------------------------------------------------------------------------
// ws_kernel: ranking vector in fp32. Also zeros tmat (memset folded in) and
// (R21) pre-converts Wo -> bf16 (wobf) so out_fused can DMA-stage it.
// grid (B), block 1024. R16 (kept): Wq row-loads hoisted; bit-identical.
// ---------------------------------------------------------------------------
__global__ __launch_bounds__(1024) void ws_kernel(const float* __restrict__ partial,
                                                  const float* __restrict__ Wq,
                                                  const float* __restrict__ bq,
                                                  const float* __restrict__ Wk,
                                                  const float* __restrict__ Wo,
                                                  float* __restrict__ ws,
                                                  float* __restrict__ tmat,
                                                  ushort_t* __restrict__ wobf) {
    const int b = blockIdx.x;
    __shared__ float xs[256];
    __shared__ float qs[256];
    __shared__ float ppart[4][256];
    const int t = threadIdx.x;
    {
        float* tz = tmat + (size_t)b * NLM * 256;
        for (int i = t; i < NLM * 256; i += 1024) tz[i] = 0.f;
    }
    {
        // Wo -> bf16 once (R21): 2048 threads x 32 elems = 65536. Same f2bf
        // as the old inline conversion -> identical bits downstream.
        const int base = (b * 1024 + t) * 32;
#pragma unroll
        for (int i = 0; i < 32; i += 8) {
            const float4 a = *(const float4*)&Wo[base + i];
            const float4 c = *(const float4*)&Wo[base + i + 4];
            uint4 o;
            o.x = f2bf(a.x) | ((unsigned)f2bf(a.y) << 16);
            o.y = f2bf(a.z) | ((unsigned)f2bf(a.w) << 16);
            o.z = f2bf(c.x) | ((unsigned)f2bf(c.y) << 16);
            o.w = f2bf(c.z) | ((unsigned)f2bf(c.w) << 16);
            *(uint4*)&wobf[base + i] = o;
        }
    }
    {
        const int c = t & 255, qd = t >> 8;
        const float* pb = partial + ((size_t)b * NCBLK + qd * 64) * 256 + c;
        float a = 0.f;
#pragma unroll 8
        for (int i = 0; i < 64; i++) a += pb[(size_t)i * 256];
        ppart[qd][c] = a;
    }
    __syncthreads();
    if (t < 256) xs[t] = ppart[0][t] + ppart[1][t] + ppart[2][t] + ppart[3][t];
    __syncthreads();
    const int lane = t & 63, w = t >> 6;
    {
        float4 wq[16];
#pragma unroll
        for (int g = 0; g < 16; g++)
            wq[g] = *(const float4*)&Wq[(size_t)(w * 16 + g) * 256 + lane * 4];
        const float4 x4 = *(const float4*)&xs[lane * 4];
#pragma unroll
        for (int g = 0; g < 16; g++) {
            const int o = w * 16 + g;
            float d = wq[g].x * x4.x + wq[g].y * x4.y + wq[g].z * x4.z + wq[g].w * x4.w;
#pragma unroll
            for (int off = 32; off >= 1; off >>= 1) d += __shfl_down(d, off);
            if (lane == 0) qs[o] = d + 8192.0f * bq[o];
        }
    }
    __syncthreads();
    const int c = t & 255, part = t >> 8;
    float a = 0.f;
#pragma unroll 16
    for (int o = part * 64; o < part * 64 + 64; o++)
        a += Wk[(size_t)o * 256 + c] * qs[o];
    ppart[part][c] = a;
    __syncthreads();
    if (t < 256)
        ws[b * 256 + t] = ppart[0][t] + ppart[1][t] + ppart[2][t] + ppart[3][t];
}

// ---------------------------------------------------------------------------
// gemm_qkv_score: grid 1280 linear.
// R22: proj tiles enlarged 128x64 -> 128x128 (bx in {0,1}): per-wave MFMA per
// barrier-pair doubles (16->32), W re-staging halves, blocks 2048->1280.
// acc[2][8] (64 VGPR), LDS 34.8 KB (staging 32 KB; epilogue Es[128][136]).
// K-order / A-B bits / epilogue association unchanged -> bit-identical.
// XCD-bijective swizzle rebuilt for 1280 (q=160): wg = (lin%8)*160 + lin/8.
//   wg <  768: proj (z = wg>>8, by = (wg&255)>>1, bx = wg&1)
//   wg >= 768: score slice blk = wg-768 (fp32 ranking path, unchanged)
// ---------------------------------------------------------------------------
__global__ __launch_bounds__(256) void gemm_qkv_score(const ushort_t* __restrict__ xbf,
                                                      const float* __restrict__ Wq,
                                                      const float* __restrict__ Wk,
                                                      const float* __restrict__ Wv,
                                                      const float* __restrict__ bq,
                                                      const float* __restrict__ bk,
                                                      const float* __restrict__ bv,
                                                      ushort_t* __restrict__ qkv,
                                                      const float* __restrict__ query,
                                                      const float* __restrict__ ws,
                                                      float* __restrict__ score) {
    __shared__ __align__(16) char smem[34816];
    ushort_t* As = (ushort_t*)smem;            // [128][64] bf16, 16 KB
    ushort_t* Bs = (ushort_t*)(smem + 16384);  // [128][64] bf16, 16 KB
    ushort_t* Es = (ushort_t*)smem;            // epilogue [128][136], 34 KB
    // XCD-bijective swizzle (1280 = 8 * 160)
    const int lin = blockIdx.x;
    const int wg = (lin & 7) * 160 + (lin >> 3);
    const int t = threadIdx.x;
    const int lane = t & 63;
    const int w = t >> 6;

    if (wg >= 768) {  // score slice (fp32 ranking path)
        const int blk = wg - 768;                         // 0..511
#pragma unroll
        for (int i = 0; i < 8; i++) {
            const int g = blk * 32 + i * 4 + w;           // row 0..16383
            const int b = g >> 13;
            const int m = g & 8191;
            const float4 kv = *(const float4*)&query[(size_t)g * 256 + lane * 4];
            const float4 qs = *(const float4*)&ws[b * 256 + lane * 4];
            float d = kv.x * qs.x + kv.y * qs.y + kv.z * qs.z + kv.w * qs.w;
#pragma unroll
            for (int off = 32; off >= 1; off >>= 1) d += __shfl_down(d, off);
            if (lane == 0) score[(size_t)b * SEQ + m] = d * INV_SCALE;
        }
        return;
    }

    const int z = wg >> 8;            // 0..2
    const int rem = wg & 255;
    const int by = rem >> 1;          // 0..127
    const int bx = rem & 1;           // 0..1
    const float* __restrict__ W = (z == 0) ? Wq : (z == 1) ? Wk : Wv;
    const float* __restrict__ bias = (z == 0) ? bq : (z == 1) ? bk : bv;
    ushort_t* __restrict__ out = qkv + (size_t)z * MROWS * 256;
    const int o0 = bx * 128;
    const int m0 = by * 128;
    const int quad = lane >> 4;
    const int l16 = lane & 15;
    const int xsw = l16 & 7;     // frag-read chunk XOR (== row&7 for A and B)

    floatx4 acc[2][8];
#pragma unroll
    for (int rt = 0; rt < 2; rt++)
#pragma unroll
        for (int ct = 0; ct < 8; ct++) acc[rt][ct] = (floatx4){0.f, 0.f, 0.f, 0.f};

    for (int kc = 0; kc < 256; kc += 64) {
        // A: 16 x 1KB global_load_lds; wave w stages its own rows w*32..+31.
#pragma unroll
        for (int q = 0; q < 4; q++) {
            const int r0 = w * 32 + q * 8;
            gload_lds16(&xbf[(size_t)(m0 + r0 + (lane >> 3)) * 256 + kc +
                             (((lane & 7) ^ (lane >> 3)) * 8)],
                        &As[r0 * 64]);
        }
        // B: reg-stage fp32 -> bf16, 4 uint4/thread (128 rows x 8 chunks),
        // XOR-swizzled ds_write
#pragma unroll
        for (int u = 0; u < 4; u++) {
            const int cid = t + u * 256;     // 0..1023
            const int row = cid >> 3;        // 0..127
            const int cch = cid & 7;         // source chunk 0..7
            const float* wp = &W[(size_t)(o0 + row) * 256 + kc + cch * 8];
            const float4 a = *(const float4*)wp;
            const float4 c = *(const float4*)(wp + 4);
            uint4 o;
            o.x = f2bf(a.x) | ((unsigned)f2bf(a.y) << 16);
            o.y = f2bf(a.z) | ((unsigned)f2bf(a.w) << 16);
            o.z = f2bf(c.x) | ((unsigned)f2bf(c.y) << 16);
            o.w = f2bf(c.z) | ((unsigned)f2bf(c.w) << 16);
            *(uint4*)&Bs[row * 64 + ((cch ^ (row & 7)) * 8)] = o;
        }
        __syncthreads();
#pragma unroll
        for (int s = 0; s < 2; s++) {
            short8 a[2];
#pragma unroll
            for (int rt = 0; rt < 2; rt++)
                a[rt] = *(const short8*)&As[(w * 32 + rt * 16 + l16) * 64 +
                                            (((s * 4 + quad) ^ xsw) * 8)];
#pragma unroll
            for (int ct = 0; ct < 8; ct++) {
                const short8 bf = *(const short8*)&Bs[(ct * 16 + l16) * 64 +
                                                      (((s * 4 + quad) ^ xsw) * 8)];
#pragma unroll
                for (int rt = 0; rt < 2; rt++)
                    acc[rt][ct] = __builtin_amdgcn_mfma_f32_16x16x32_bf16(
                        a[rt], bf, acc[rt][ct], 0, 0, 0);
            }
        }
        __syncthreads();
    }

    // Epilogue: bias + bf16 into Es (stride 136), then coalesced uint4 stores
#pragma unroll
    for (int rt = 0; rt < 2; rt++) {
#pragma unroll
        for (int ct = 0; ct < 8; ct++) {
            const int col = ct * 16 + l16;      // 0..127
            const float bb = bias[o0 + col];
#pragma unroll
            for (int reg = 0; reg < 4; reg++) {
                const int row = w * 32 + rt * 16 + quad * 4 + reg;
                Es[row * 136 + col] = f2bf(acc[rt][ct][reg] + bb);
            }
        }
    }
    __syncthreads();
#pragma unroll
    for (int u = 0; u < 8; u++) {
        const int cid = t + u * 256;            // 0..2047
        const int row = cid >> 4;               // 0..127
        const int off = (cid & 15) * 8;         // 0..120 (ushorts)
        *(uint4*)&out[(size_t)(m0 + row) * 256 + o0 + off] =
            *(const uint4*)&Es[row * 136 + off];
    }
}

// ---------------------------------------------------------------------------
// Top-40 + gather via RADIX-SELECT. grid (B), block 1024.
// R20 (kept): wave-parallel suffix-scan digit selection (identical set).
// R14: sel bf16 (lossless), padded to NLMP=48 rows.
// ---------------------------------------------------------------------------
__global__ __launch_bounds__(1024) void topk_gather(const float* __restrict__ score,
                                                    const ushort_t* __restrict__ kmat,
                                                    ushort_t* __restrict__ sel) {
    const int b = blockIdx.x;
    const int t = threadIdx.x;
    __shared__ unsigned hist[256];
    __shared__ unsigned sPrefix, sMask, sRem, sNeq;
    __shared__ int sNgt;
    __shared__ int top[NLM];
    __shared__ unsigned topkey[NLM];

    unsigned key[8];
#pragma unroll
    for (int j = 0; j < 8; j++) {
        const unsigned u = __float_as_uint(score[(size_t)b * SEQ + t + j * 1024]);
        key[j] = u ^ (unsigned)(((int)u >> 31) | 0x80000000);
    }
    if (t == 0) { sPrefix = 0; sMask = 0; sRem = NLM; sNgt = 0; sNeq = 0; }

    for (int lvl = 0; lvl < 4; lvl++) {
        const int shift = 24 - 8 * lvl;
        if (t < 256) hist[t] = 0;
        __syncthreads();
        const unsigned pfx = sPrefix, msk = sMask;
#pragma unroll
        for (int j = 0; j < 8; j++)
            if (((key[j] ^ pfx) & msk) == 0)
                atomicAdd(&hist[(key[j] >> shift) & 255u], 1u);
        __syncthreads();
        if (t < 64) {  // wave 0 only
            unsigned sfx = hist[t * 4] + hist[t * 4 + 1] + hist[t * 4 + 2] + hist[t * 4 + 3];
#pragma unroll
            for (int off = 1; off < 64; off <<= 1) {
                const unsigned o = __shfl_down(sfx, off);
                if (t + off < 64) sfx += o;
            }
            const unsigned rem = sRem;
            const unsigned long long mk = __ballot(sfx >= rem);
            const int gstar = 63 - __builtin_clzll(mk);
            unsigned S1 = __shfl(sfx, (gstar + 1) & 63);
            if (gstar == 63) S1 = 0u;
            if (t == 0) {
                int d = gstar * 4 + 3;
                unsigned cum = S1;
                for (; d > gstar * 4; d--) { if (cum + hist[d] >= rem) break; cum += hist[d]; }
                sRem = rem - cum;
                sPrefix |= ((unsigned)d) << shift;
                sMask |= 255u << shift;
            }
        }
        __syncthreads();
    }
    const unsigned K40 = sPrefix;
    const unsigned rem = sRem;
    const int ngt = NLM - (int)rem;

#pragma unroll
    for (int j = 0; j < 8; j++) {
        if (key[j] > K40) {
            const int slot = atomicAdd(&sNgt, 1);
            top[slot] = t + j * 1024; topkey[slot] = key[j];
        } else if (key[j] == K40) {
            const unsigned e = atomicAdd(&sNeq, 1u);
            if (e < rem) {
                const int slot = ngt + (int)e;
                top[slot] = t + j * 1024; topkey[slot] = key[j];
            }
        }
    }
    __syncthreads();

    if (t < 64) {
        unsigned long long c = (t < NLM)
            ? ((((unsigned long long)(~topkey[t])) << 32) | (unsigned)top[t])
            : 0xFFFFFFFFFFFFFFFFull;
#pragma unroll
        for (int kk = 2; kk <= 64; kk <<= 1) {
#pragma unroll
            for (int j = kk >> 1; j >= 1; j >>= 1) {
                const unsigned long long o = __shfl_xor(c, j);
                const bool takeMin = ((t & kk) == 0) == ((t & j) == 0);
                const bool less = c < o;
                c = (takeMin == less) ? c : o;
            }
        }
        if (t < NLM) top[t] = (int)(c & 0xFFFFFFFFu);
    }
    __syncthreads();

    for (int f = t; f < NLMP * 256; f += 1024) {
        const int j = f >> 8;
        const int cc = f & 255;
        sel[(size_t)b * NLMP * 256 + f] =
            (j < NLM) ? kmat[((size_t)b * SEQ + top[j]) * 256 + cc] : (ushort_t)0;
    }
}

// ---------------------------------------------------------------------------
// sim_fused: grid (SEQ/64, B, 2), block 256 (4 waves). R15/R17 structure
// (measured-best). Phase A on bf16 MFMA, DIRECT-from-global frags; softmax on
// MFMA C-layout via shfl_xor row-reduce; cols 40..47 masked.
//   z=0: probs -> simq.   z=1: probs -> Ps LDS, V via global_load_lds,
// broadcast-FMA into tac[40], one atomicAdd batch per block.
// ---------------------------------------------------------------------------
__global__ __launch_bounds__(256, 4) void sim_fused(const ushort_t* __restrict__ qbf,
                                                    const ushort_t* __restrict__ kbf,
                                                    const ushort_t* __restrict__ vbf,
                                                    const ushort_t* __restrict__ sel,
                                                    float* __restrict__ simq,
                                                    float* __restrict__ tmat) {
    __shared__ __align__(16) char smem[43008];
    float (*Ps)[40]  = (float(*)[40])smem;              // 10240 B (z=1 only)
    ushort_t* Vs     = (ushort_t*)(smem + 10240);       // 32768 B (z=1 only)
    const int b = blockIdx.y;
    const int n0 = blockIdx.x * 64;
    const int t = threadIdx.x;
    const int lane = t & 63;
    const int w = t >> 6;           // wave id = M-tile (16 rows each)
    const int quad = lane >> 4;
    const int l16 = lane & 15;
    const ushort_t* __restrict__ A = (blockIdx.z == 0) ? qbf : kbf;
    const ushort_t* __restrict__ Arow = A + ((size_t)b * SEQ + n0 + w * 16 + l16) * 256;
    const ushort_t* __restrict__ Sb = sel + (size_t)b * NLMP * 256 + (size_t)l16 * 256;

    floatx4 acc[3];
#pragma unroll
    for (int ct = 0; ct < 3; ct++) acc[ct] = (floatx4){0.f, 0.f, 0.f, 0.f};

#pragma unroll
    for (int ks = 0; ks < 8; ks++) {
        const int ko = ks * 32 + quad * 8;
        const short8 a  = *(const short8*)&Arow[ko];
        const short8 b0 = *(const short8*)&Sb[ko];
        const short8 b1 = *(const short8*)&Sb[16 * 256 + ko];
        const short8 b2 = *(const short8*)&Sb[32 * 256 + ko];
        acc[0] = __builtin_amdgcn_mfma_f32_16x16x32_bf16(a, b0, acc[0], 0, 0, 0);
        acc[1] = __builtin_amdgcn_mfma_f32_16x16x32_bf16(a, b1, acc[1], 0, 0, 0);
        acc[2] = __builtin_amdgcn_mfma_f32_16x16x32_bf16(a, b2, acc[2], 0, 0, 0);
    }

    // Softmax over 40 landmark cols, per output row (= w*16 + quad*4 + reg).
    const bool v2ok = (l16 < 8);    // ct==2 col = 32+l16 valid iff < 40
    float p0[4], p1[4], p2[4];
#pragma unroll
    for (int reg = 0; reg < 4; reg++) {
        const float l0 = acc[0][reg] * INV_SCALE;
        const float l1 = acc[1][reg] * INV_SCALE;
        const float l2 = acc[2][reg] * INV_SCALE;
        float m = fmaxf(l0, l1);
        if (v2ok) m = fmaxf(m, l2);
        m = fmaxf(m, __shfl_xor(m, 1));
        m = fmaxf(m, __shfl_xor(m, 2));
        m = fmaxf(m, __shfl_xor(m, 4));
        m = fmaxf(m, __shfl_xor(m, 8));
        const float e0 = expf(l0 - m);
        const float e1 = expf(l1 - m);
        const float e2 = v2ok ? expf(l2 - m) : 0.f;
        float s = e0 + e1 + e2;
        s += __shfl_xor(s, 1);
        s += __shfl_xor(s, 2);
        s += __shfl_xor(s, 4);
        s += __shfl_xor(s, 8);
        const float inv = 1.f / s;
        p0[reg] = e0 * inv; p1[reg] = e1 * inv; p2[reg] = e2 * inv;
    }

    const int row0 = w * 16 + quad * 4;
    if (blockIdx.z == 0) {
        float* __restrict__ dst = &simq[((size_t)b * SEQ + n0 + row0) * NLM];
#pragma unroll
        for (int reg = 0; reg < 4; reg++) {
            float* __restrict__ d2 = dst + reg * NLM;
            d2[l16] = p0[reg];
            d2[16 + l16] = p1[reg];
            if (v2ok) d2[32 + l16] = p2[reg];
        }
        return;
    }

    // ---- z=1: probs -> Ps, then tmat accumulation in-place (R11 phase B) ----
#pragma unroll
    for (int reg = 0; reg < 4; reg++) {
        Ps[row0 + reg][l16] = p0[reg];
        Ps[row0 + reg][16 + l16] = p1[reg];
        if (v2ok) Ps[row0 + reg][32 + l16] = p2[reg];
    }
    // V-stage: 8 x 1KB global_load_lds per wave; wave w rows {w*2+u*8 +0..1}
#pragma unroll
    for (int u = 0; u < 8; u++) {
        gload_lds16(&vbf[((size_t)b * SEQ + n0 + w * 2 + u * 8 + (lane >> 5)) * 256 +
                         (lane & 31) * 8],
                    &Vs[(w * 2 + u * 8) * 256]);
    }
    __syncthreads();

    float tac[40];
#pragma unroll
    for (int j = 0; j < 40; j++) tac[j] = 0.f;

#pragma unroll 2
    for (int m = 0; m < 64; m++) {
        const float vv = bf2f(Vs[m * 256 + t]);   // 2-way bank alias: free
#pragma unroll
        for (int j4 = 0; j4 < 10; j4++) {
            const float4 p = *(const float4*)&Ps[m][j4 * 4];  // broadcast
            tac[j4 * 4 + 0] = fmaf(p.x, vv, tac[j4 * 4 + 0]);
            tac[j4 * 4 + 1] = fmaf(p.y, vv, tac[j4 * 4 + 1]);
            tac[j4 * 4 + 2] = fmaf(p.z, vv, tac[j4 * 4 + 2]);
            tac[j4 * 4 + 3] = fmaf(p.w, vv, tac[j4 * 4 + 3]);
        }
    }
#pragma unroll
    for (int j = 0; j < 40; j++)
        atomicAdd(&tmat[(size_t)b * NLM * 256 + j * 256 + t], tac[j]);
}

// ---------------------------------------------------------------------------
// out_fused v4 (R21, kept): grid 512 (32 rows/block), block 512 (8 waves),
// 54 KB LDS -> 2 blocks/CU. OP once per col; Bs via gload_lds16 DMA from
// precomputed wobf. Bit-identical to the R19/R20 out path.
// ---------------------------------------------------------------------------
__global__ __launch_bounds__(512) void out_fused(const float* __restrict__ simq,
                                                 const float* __restrict__ tmat,
                                                 const ushort_t* __restrict__ wobf,
                                                 const float* __restrict__ bias,
                                                 const float* __restrict__ resid,
                                                 float* __restrict__ out) {
    __shared__ __align__(16) char smem[54272];
    float* Ps = (float*)smem;                      // [32*40] fp32   5120 B
    ushort_t* Ac = (ushort_t*)(smem + 5120);       // [32][256] bf16 16384 B
    ushort_t* Bs = (ushort_t*)(smem + 21504);      // [256][64] bf16 32768 B

    const int t = threadIdx.x;
    const int m0 = blockIdx.x * 32;
    const int b = blockIdx.x >> 8;                 // 256 blocks per batch
    const int lane = t & 63;
    const int w = t >> 6;                          // 0..7
    const int quad = lane >> 4;
    const int l16 = lane & 15;
    const int xsw = l16 & 7;
    const int rt_base = (w & 1) * 16;              // wave row tile (0 or 16)
    const int cg_base = (w >> 1) * 4;              // wave col-tile base (x4 of 16)

    // ---- prologue: stage simq tile ----
    for (int f = t; f < 32 * NLM; f += 512)
        Ps[f] = simq[(size_t)m0 * NLM + f];
    __syncthreads();

    // ---- OP once: thread -> col, 16 rows ----
    {
        const int col = t & 255;
        const int r0 = (t >> 8) * 16;
        const float* __restrict__ Tb = tmat + (size_t)b * NLM * 256;
        float tc[40];
#pragma unroll
        for (int l = 0; l < 40; l++) tc[l] = Tb[l * 256 + col];
        const int chunk = col >> 3;
#pragma unroll
        for (int r = 0; r < 16; r++) {
            const int rr = r0 + r;
            float a = 0.f;
#pragma unroll
            for (int j4 = 0; j4 < 10; j4++) {
                const float4 p = *(const float4*)&Ps[rr * 40 + j4 * 4];
                a = fmaf(p.x, tc[j4 * 4 + 0], a);
                a = fmaf(p.y, tc[j4 * 4 + 1], a);
                a = fmaf(p.z, tc[j4 * 4 + 2], a);
                a = fmaf(p.w, tc[j4 * 4 + 3], a);
            }
            const int pch = (chunk & ~7) | ((chunk & 7) ^ (rr & 7));
            Ac[rr * 256 + pch * 8 + (col & 7)] = f2bf(a);
        }
    }

    floatx4 acc[4];
#pragma unroll
    for (int ct = 0; ct < 4; ct++) acc[ct] = (floatx4){0.f, 0.f, 0.f, 0.f};

    for (int kc = 0; kc < 256; kc += 64) {
        // Bs stage: DMA from wobf (bf16), XOR source-swizzle; wave w stages
        // rows (= output cols) w*32..+31 in 4 calls of 8 rows.
#pragma unroll
        for (int q = 0; q < 4; q++) {
            const int r0 = w * 32 + q * 8;
            gload_lds16(&wobf[(size_t)(r0 + (lane >> 3)) * 256 + kc +
                              (((lane & 7) ^ (lane >> 3)) * 8)],
                        &Bs[r0 * 64]);
        }
        __syncthreads();   // drains gload; also orders Ac writes (first iter)
#pragma unroll
        for (int s = 0; s < 2; s++) {
            // A-frag from Ac: row rt_base+l16, phys chunk (kc>>3)+((s*4+quad)^xsw)
            // -> logical chunk (kc>>3)+(s*4+quad) after write-side XOR cancels.
            const short8 a = *(const short8*)&Ac[(rt_base + l16) * 256 +
                                                 ((kc >> 3) + ((s * 4 + quad) ^ xsw)) * 8];
#pragma unroll
            for (int ct = 0; ct < 4; ct++) {
                const short8 bf = *(const short8*)&Bs[((cg_base + ct) * 16 + l16) * 64 +
                                                      (((s * 4 + quad) ^ xsw) * 8)];
                acc[ct] = __builtin_amdgcn_mfma_f32_16x16x32_bf16(a, bf, acc[ct], 0, 0, 0);
            }
        }
        __syncthreads();
    }

    // Epilogue: direct stores from MFMA C-layout. (acc + bias) + resid.
#pragma unroll
    for (int ct = 0; ct < 4; ct++) {
        const int col = (cg_base + ct) * 16 + l16;
        const float bb = bias[col];
#pragma unroll
        for (int reg = 0; reg < 4; reg++) {
            const int row = rt_base + quad * 4 + reg;
            const size_t idx = (size_t)(m0 + row) * 256 + col;
            out[idx] = (acc[ct][reg] + bb) + resid[idx];
        }
    }
}

// ---------------------------------------------------------------------------
// Workspace (~37 MB). 6 dispatches. R22: gemm_qkv 128x128 tiles (2x MFMA
// per barrier-pair, bit-identical). out_fused/ws/topk/sim unchanged from R21.
// ---------------------------------------------------------------------------
extern "C" void kernel_launch(void* const* d_in, const int* in_sizes, int n_in,
                              void* d_out, int out_size, void* d_ws, size_t ws_size,
                              hipStream_t stream) {
    const float* query = (const float*)d_in[0];
    const float* Wq = (const float*)d_in[1];
    const float* bq = (const float*)d_in[2];
    const float* Wk = (const float*)d_in[3];
    const float* bk = (const float*)d_in[4];
    const float* Wv = (const float*)d_in[5];
    const float* bv = (const float*)d_in[6];
    const float* Wo = (const float*)d_in[7];
    const float* bo = (const float*)d_in[8];
    float* out = (float*)d_out;

    char* p = (char*)d_ws;
    float* simq  = (float*)p;            p += (size_t)MROWS * NLM * 4;      // 2.62 MB
    ushort_t* selbf = (ushort_t*)p;      p += (size_t)BATCH * NLMP * 256 * 2;
    float* tmat  = (float*)p;            p += (size_t)BATCH * NLM * 256 * 4;
    float* partial = (float*)p;          p += (size_t)BATCH * NCBLK * 256 * 4; // 512 KB
    float* ws    = (float*)p;            p += (size_t)BATCH * 256 * 4;
    float* score = (float*)p;            p += (size_t)BATCH * SEQ * 4;
    ushort_t* wobf = (ushort_t*)p;       p += (size_t)256 * 256 * 2;        // 128 KB
    ushort_t* qkv = (ushort_t*)p;        p += (size_t)3 * MROWS * 256 * 2;  // 25.2 MB
    ushort_t* xbf = (ushort_t*)p;        p += (size_t)MROWS * 256 * 2;      // 8.39 MB
    ushort_t* qbf = qkv;
    ushort_t* kbf = qkv + (size_t)MROWS * 256;
    ushort_t* vbf = qkv + (size_t)2 * MROWS * 256;

    const dim3 blk(256);

    convert_colsum<<<dim3(SEQ / 32, BATCH), blk, 0, stream>>>(query, xbf, partial);
    ws_kernel<<<dim3(BATCH), dim3(1024), 0, stream>>>(partial, Wq, bq, Wk, Wo, ws, tmat, wobf);

    gemm_qkv_score<<<dim3(1280), blk, 0, stream>>>(
        xbf, Wq, Wk, Wv, bq, bk, bv, qkv, query, ws, score);

    topk_gather<<<dim3(BATCH), dim3(1024), 0, stream>>>(score, kbf, selbf);

    sim_fused<<<dim3(SEQ / 64, BATCH, 2), blk, 0, stream>>>(qbf, kbf, vbf, selbf, simq, tmat);

    out_fused<<<dim3(MROWS / 32), dim3(512), 0, stream>>>(simq, tmat, wobf, bo, query, out);
}

// Round 14
// 178.197 us; speedup vs baseline: 1.0638x; 1.0638x over previous
//
#include <hip/hip_runtime.h>
#include <cstddef>
#include <cstdint>

// Problem constants (match reference)
#define BATCH 2
#define SEQ 8192
#define CH 256
#define NLM 40
#define NLMP 48               // landmark rows padded to 3 MFMA N-tiles
#define MROWS (BATCH * SEQ)   // 16384
#define INV_SCALE 0.0625f     // 1/sqrt(256)
#define NCBLK 256             // convert_colsum blocks per batch (SEQ/32)

typedef unsigned short ushort_t;
typedef __attribute__((ext_vector_type(8))) short short8;    // 8 bf16 (4 VGPRs)
typedef __attribute__((ext_vector_type(4))) float floatx4;   // MFMA acc

// round-to-nearest-even fp32 -> bf16
__device__ __forceinline__ ushort_t f2bf(float f) {
    unsigned int u = __float_as_uint(f);
    u += 0x7FFFu + ((u >> 16) & 1u);
    return (ushort_t)(u >> 16);
}
__device__ __forceinline__ float bf2f(ushort_t u) {
    return __uint_as_float(((unsigned)u) << 16);
}

// async global->LDS, 16B per lane. LDS dest = wave-uniform base + lane*16
// (m104); global src is per-lane. Drained by __syncthreads (vmcnt0 before
// barrier).
__device__ __forceinline__ void gload_lds16(const ushort_t* g, ushort_t* l) {
    __builtin_amdgcn_global_load_lds(
        (const __attribute__((address_space(1))) unsigned int*)g,
        (__attribute__((address_space(3))) unsigned int*)l, 16, 0, 0);
}

// ---------------------------------------------------------------------------
// convert_colsum: xbf = bf16(x); partial[b][blk][c] = sum of 32 rows of col c.
// grid (SEQ/32, B) = 512 blocks, block 256.
// ---------------------------------------------------------------------------
__global__ __launch_bounds__(256) void convert_colsum(const float* __restrict__ x,
                                                      ushort_t* __restrict__ xbf,
                                                      float* __restrict__ partial) {
    __shared__ float red[4][256];
    const int b = blockIdx.y;
    const int r0 = blockIdx.x * 32;
    const int t = threadIdx.x;
    const int c4 = (t & 63) * 4;     // 0..252
    const int rg = t >> 6;           // 0..3
    const float* base = x + ((size_t)b * SEQ + r0) * 256;
    ushort_t* obase = xbf + ((size_t)b * SEQ + r0) * 256;
    float4 s = {0.f, 0.f, 0.f, 0.f};
#pragma unroll
    for (int i = 0; i < 8; i++) {
        const int r = rg + i * 4;    // 0..31
        const float4 a = *(const float4*)&base[(size_t)r * 256 + c4];
        uint2 o;
        o.x = f2bf(a.x) | ((unsigned)f2bf(a.y) << 16);
        o.y = f2bf(a.z) | ((unsigned)f2bf(a.w) << 16);
        *(uint2*)&obase[(size_t)r * 256 + c4] = o;
        s.x += a.x; s.y += a.y; s.z += a.z; s.w += a.w;
    }
    *(float4*)&red[rg][c4] = s;
    __syncthreads();
    const float tot = red[0][t] + red[1][t] + red[2][t] + red[3][t];
    partial[((size_t)b * NCBLK + blockIdx.x) * 256 + t] = tot;
}

// ---------------------------------------------------------------------------
// ws_kernel: ranking vector in fp32. Also zeros tmat (memset folded in) and
// (R21) pre-converts Wo -> bf16 (wobf) so out_fused can DMA-stage it.
// grid (B), block 1024. R16 (kept): Wq row-loads hoisted; bit-identical.
// ---------------------------------------------------------------------------
__global__ __launch_bounds__(1024) void ws_kernel(const float* __restrict__ partial,
                                                  const float* __restrict__ Wq,
                                                  const float* __restrict__ bq,
                                                  const float* __restrict__ Wk,
                                                  const float* __restrict__ Wo,
                                                  float* __restrict__ ws,
                                                  float* __restrict__ tmat,
                                                  ushort_t* __restrict__ wobf) {
    const int b = blockIdx.x;
    __shared__ float xs[256];
    __shared__ float qs[256];
    __shared__ float ppart[4][256];
    const int t = threadIdx.x;
    {
        float* tz = tmat + (size_t)b * NLM * 256;
        for (int i = t; i < NLM * 256; i += 1024) tz[i] = 0.f;
    }
    {
        // Wo -> bf16 once (R21): 2048 threads x 32 elems = 65536. Same f2bf
        // as the old inline conversion -> identical bits downstream.
        const int base = (b * 1024 + t) * 32;
#pragma unroll
        for (int i = 0; i < 32; i += 8) {
            const float4 a = *(const float4*)&Wo[base + i];
            const float4 c = *(const float4*)&Wo[base + i + 4];
            uint4 o;
            o.x = f2bf(a.x) | ((unsigned)f2bf(a.y) << 16);
            o.y = f2bf(a.z) | ((unsigned)f2bf(a.w) << 16);
            o.z = f2bf(c.x) | ((unsigned)f2bf(c.y) << 16);
            o.w = f2bf(c.z) | ((unsigned)f2bf(c.w) << 16);
            *(uint4*)&wobf[base + i] = o;
        }
    }
    {
        const int c = t & 255, qd = t >> 8;
        const float* pb = partial + ((size_t)b * NCBLK + qd * 64) * 256 + c;
        float a = 0.f;
#pragma unroll 8
        for (int i = 0; i < 64; i++) a += pb[(size_t)i * 256];
        ppart[qd][c] = a;
    }
    __syncthreads();
    if (t < 256) xs[t] = ppart[0][t] + ppart[1][t] + ppart[2][t] + ppart[3][t];
    __syncthreads();
    const int lane = t & 63, w = t >> 6;
    {
        float4 wq[16];
#pragma unroll
        for (int g = 0; g < 16; g++)
            wq[g] = *(const float4*)&Wq[(size_t)(w * 16 + g) * 256 + lane * 4];
        const float4 x4 = *(const float4*)&xs[lane * 4];
#pragma unroll
        for (int g = 0; g < 16; g++) {
            const int o = w * 16 + g;
            float d = wq[g].x * x4.x + wq[g].y * x4.y + wq[g].z * x4.z + wq[g].w * x4.w;
#pragma unroll
            for (int off = 32; off >= 1; off >>= 1) d += __shfl_down(d, off);
            if (lane == 0) qs[o] = d + 8192.0f * bq[o];
        }
    }
    __syncthreads();
    const int c = t & 255, part = t >> 8;
    float a = 0.f;
#pragma unroll 16
    for (int o = part * 64; o < part * 64 + 64; o++)
        a += Wk[(size_t)o * 256 + c] * qs[o];
    ppart[part][c] = a;
    __syncthreads();
    if (t < 256)
        ws[b * 256 + t] = ppart[0][t] + ppart[1][t] + ppart[2][t] + ppart[3][t];
}

// ---------------------------------------------------------------------------
// gemm_qkv_score: grid 2048 linear (logical (4, 128, 4)).
// R23: REVERT to the R21 config (128x64 tiles) — R22's 128x128 tiles
// regressed +13 us (VGPR-occupancy loss > barrier-amortization gain; same
// lesson as R16: parallelism beats per-block efficiency here).
// R18 (kept): T1 XCD-bijective block swizzle. Pure index permutation.
//   z<3: q/k/v projection (R15: BK=64 + global_load_lds + XOR source-swizzle).
//   z=3: score slice — fp32 ranking path.
// ---------------------------------------------------------------------------
__global__ __launch_bounds__(256) void gemm_qkv_score(const ushort_t* __restrict__ xbf,
                                                      const float* __restrict__ Wq,
                                                      const float* __restrict__ Wk,
                                                      const float* __restrict__ Wv,
                                                      const float* __restrict__ bq,
                                                      const float* __restrict__ bk,
                                                      const float* __restrict__ bv,
                                                      ushort_t* __restrict__ qkv,
                                                      const float* __restrict__ query,
                                                      const float* __restrict__ ws,
                                                      float* __restrict__ score) {
    __shared__ __align__(16) char smem[24576];
    ushort_t* As = (ushort_t*)smem;            // [128][64] bf16, 16 KB
    ushort_t* Bs = (ushort_t*)(smem + 16384);  // [64][64]  bf16,  8 KB
    ushort_t* Es = (ushort_t*)smem;            // epilogue [128][72], 18 KB
    // XCD-bijective swizzle (2048 % 8 == 0)
    const int lin = blockIdx.x;
    const int wg = (lin & 7) * 256 + (lin >> 3);
    const int bx = wg & 3;            // o0 index 0..3
    const int by = (wg >> 2) & 127;   // m0 index 0..127
    const int z = wg >> 9;            // 0..3
    const int t = threadIdx.x;
    const int lane = t & 63;
    const int w = t >> 6;

    if (z == 3) {  // score slice (fp32 ranking path)
        const int blk = by * 4 + bx;                      // 0..511
#pragma unroll
        for (int i = 0; i < 8; i++) {
            const int g = blk * 32 + i * 4 + w;           // row 0..16383
            const int b = g >> 13;
            const int m = g & 8191;
            const float4 kv = *(const float4*)&query[(size_t)g * 256 + lane * 4];
            const float4 qs = *(const float4*)&ws[b * 256 + lane * 4];
            float d = kv.x * qs.x + kv.y * qs.y + kv.z * qs.z + kv.w * qs.w;
#pragma unroll
            for (int off = 32; off >= 1; off >>= 1) d += __shfl_down(d, off);
            if (lane == 0) score[(size_t)b * SEQ + m] = d * INV_SCALE;
        }
        return;
    }

    const float* __restrict__ W = (z == 0) ? Wq : (z == 1) ? Wk : Wv;
    const float* __restrict__ bias = (z == 0) ? bq : (z == 1) ? bk : bv;
    ushort_t* __restrict__ out = qkv + (size_t)z * MROWS * 256;
    const int o0 = bx * 64;
    const int m0 = by * 128;
    const int quad = lane >> 4;
    const int l16 = lane & 15;
    const int xsw = l16 & 7;     // frag-read chunk XOR (== row&7 for A and B)

    floatx4 acc[2][4];
#pragma unroll
    for (int rt = 0; rt < 2; rt++)
#pragma unroll
        for (int ct = 0; ct < 4; ct++) acc[rt][ct] = (floatx4){0.f, 0.f, 0.f, 0.f};

    for (int kc = 0; kc < 256; kc += 64) {
        // A: 16 x 1KB global_load_lds; wave w stages its own rows w*32..+31.
#pragma unroll
        for (int q = 0; q < 4; q++) {
            const int r0 = w * 32 + q * 8;
            gload_lds16(&xbf[(size_t)(m0 + r0 + (lane >> 3)) * 256 + kc +
                             (((lane & 7) ^ (lane >> 3)) * 8)],
                        &As[r0 * 64]);
        }
        // B: reg-stage fp32 -> bf16, 2 uint4/thread, XOR-swizzled ds_write
#pragma unroll
        for (int u = 0; u < 2; u++) {
            const int cid = t + u * 256;
            const int row = cid >> 3;        // 0..63
            const int cch = cid & 7;         // source chunk 0..7
            const float* wp = &W[(size_t)(o0 + row) * 256 + kc + cch * 8];
            const float4 a = *(const float4*)wp;
            const float4 c = *(const float4*)(wp + 4);
            uint4 o;
            o.x = f2bf(a.x) | ((unsigned)f2bf(a.y) << 16);
            o.y = f2bf(a.z) | ((unsigned)f2bf(a.w) << 16);
            o.z = f2bf(c.x) | ((unsigned)f2bf(c.y) << 16);
            o.w = f2bf(c.z) | ((unsigned)f2bf(c.w) << 16);
            *(uint4*)&Bs[row * 64 + ((cch ^ (row & 7)) * 8)] = o;
        }
        __syncthreads();
#pragma unroll
        for (int s = 0; s < 2; s++) {
            short8 a[2], bf[4];
#pragma unroll
            for (int rt = 0; rt < 2; rt++)
                a[rt] = *(const short8*)&As[(w * 32 + rt * 16 + l16) * 64 +
                                            (((s * 4 + quad) ^ xsw) * 8)];
#pragma unroll
            for (int ct = 0; ct < 4; ct++)
                bf[ct] = *(const short8*)&Bs[(ct * 16 + l16) * 64 +
                                             (((s * 4 + quad) ^ xsw) * 8)];
#pragma unroll
            for (int rt = 0; rt < 2; rt++)
#pragma unroll
                for (int ct = 0; ct < 4; ct++)
                    acc[rt][ct] = __builtin_amdgcn_mfma_f32_16x16x32_bf16(
                        a[rt], bf[ct], acc[rt][ct], 0, 0, 0);
        }
        __syncthreads();
    }

    // Epilogue: bias + bf16 into Es (stride 72), then coalesced uint4 stores
#pragma unroll
    for (int rt = 0; rt < 2; rt++) {
#pragma unroll
        for (int ct = 0; ct < 4; ct++) {
            const int col = ct * 16 + l16;
            const float bb = bias[o0 + col];
#pragma unroll
            for (int reg = 0; reg < 4; reg++) {
                const int row = w * 32 + rt * 16 + quad * 4 + reg;
                Es[row * 72 + col] = f2bf(acc[rt][ct][reg] + bb);
            }
        }
    }
    __syncthreads();
#pragma unroll
    for (int u = 0; u < 4; u++) {
        const int cid = t + u * 256;            // 0..1023
        const int row = cid >> 3;               // 0..127
        const int off = (cid & 7) * 8;          // 0..56 (ushorts)
        *(uint4*)&out[(size_t)(m0 + row) * 256 + o0 + off] =
            *(const uint4*)&Es[row * 72 + off];
    }
}

// ---------------------------------------------------------------------------
// Top-40 + gather via RADIX-SELECT. grid (B), block 1024.
// R20 (kept): wave-parallel suffix-scan digit selection (identical set).
// R14: sel bf16 (lossless), padded to NLMP=48 rows.
// ---------------------------------------------------------------------------
__global__ __launch_bounds__(1024) void topk_gather(const float* __restrict__ score,
                                                    const ushort_t* __restrict__ kmat,
                                                    ushort_t* __restrict__ sel) {
    const int b = blockIdx.x;
    const int t = threadIdx.x;
    __shared__ unsigned hist[256];
    __shared__ unsigned sPrefix, sMask, sRem, sNeq;
    __shared__ int sNgt;
    __shared__ int top[NLM];
    __shared__ unsigned topkey[NLM];

    unsigned key[8];
#pragma unroll
    for (int j = 0; j < 8; j++) {
        const unsigned u = __float_as_uint(score[(size_t)b * SEQ + t + j * 1024]);
        key[j] = u ^ (unsigned)(((int)u >> 31) | 0x80000000);
    }
    if (t == 0) { sPrefix = 0; sMask = 0; sRem = NLM; sNgt = 0; sNeq = 0; }

    for (int lvl = 0; lvl < 4; lvl++) {
        const int shift = 24 - 8 * lvl;
        if (t < 256) hist[t] = 0;
        __syncthreads();
        const unsigned pfx = sPrefix, msk = sMask;
#pragma unroll
        for (int j = 0; j < 8; j++)
            if (((key[j] ^ pfx) & msk) == 0)
                atomicAdd(&hist[(key[j] >> shift) & 255u], 1u);
        __syncthreads();
        if (t < 64) {  // wave 0 only
            unsigned sfx = hist[t * 4] + hist[t * 4 + 1] + hist[t * 4 + 2] + hist[t * 4 + 3];
#pragma unroll
            for (int off = 1; off < 64; off <<= 1) {
                const unsigned o = __shfl_down(sfx, off);
                if (t + off < 64) sfx += o;
            }
            const unsigned rem = sRem;
            const unsigned long long mk = __ballot(sfx >= rem);
            const int gstar = 63 - __builtin_clzll(mk);
            unsigned S1 = __shfl(sfx, (gstar + 1) & 63);
            if (gstar == 63) S1 = 0u;
            if (t == 0) {
                int d = gstar * 4 + 3;
                unsigned cum = S1;
                for (; d > gstar * 4; d--) { if (cum + hist[d] >= rem) break; cum += hist[d]; }
                sRem = rem - cum;
                sPrefix |= ((unsigned)d) << shift;
                sMask |= 255u << shift;
            }
        }
        __syncthreads();
    }
    const unsigned K40 = sPrefix;
    const unsigned rem = sRem;
    const int ngt = NLM - (int)rem;

#pragma unroll
    for (int j = 0; j < 8; j++) {
        if (key[j] > K40) {
            const int slot = atomicAdd(&sNgt, 1);
            top[slot] = t + j * 1024; topkey[slot] = key[j];
        } else if (key[j] == K40) {
            const unsigned e = atomicAdd(&sNeq, 1u);
            if (e < rem) {
                const int slot = ngt + (int)e;
                top[slot] = t + j * 1024; topkey[slot] = key[j];
            }
        }
    }
    __syncthreads();

    if (t < 64) {
        unsigned long long c = (t < NLM)
            ? ((((unsigned long long)(~topkey[t])) << 32) | (unsigned)top[t])
            : 0xFFFFFFFFFFFFFFFFull;
#pragma unroll
        for (int kk = 2; kk <= 64; kk <<= 1) {
#pragma unroll
            for (int j = kk >> 1; j >= 1; j >>= 1) {
                const unsigned long long o = __shfl_xor(c, j);
                const bool takeMin = ((t & kk) == 0) == ((t & j) == 0);
                const bool less = c < o;
                c = (takeMin == less) ? c : o;
            }
        }
        if (t < NLM) top[t] = (int)(c & 0xFFFFFFFFu);
    }
    __syncthreads();

    for (int f = t; f < NLMP * 256; f += 1024) {
        const int j = f >> 8;
        const int cc = f & 255;
        sel[(size_t)b * NLMP * 256 + f] =
            (j < NLM) ? kmat[((size_t)b * SEQ + top[j]) * 256 + cc] : (ushort_t)0;
    }
}

// ---------------------------------------------------------------------------
// sim_fused: grid (SEQ/64, B, 2), block 256 (4 waves). R15/R17 structure
// (measured-best). Phase A on bf16 MFMA, DIRECT-from-global frags; softmax on
// MFMA C-layout via shfl_xor row-reduce; cols 40..47 masked.
//   z=0: probs -> simq.   z=1: probs -> Ps LDS, V via global_load_lds,
// broadcast-FMA into tac[40], one atomicAdd batch per block.
// ---------------------------------------------------------------------------
__global__ __launch_bounds__(256, 4) void sim_fused(const ushort_t* __restrict__ qbf,
                                                    const ushort_t* __restrict__ kbf,
                                                    const ushort_t* __restrict__ vbf,
                                                    const ushort_t* __restrict__ sel,
                                                    float* __restrict__ simq,
                                                    float* __restrict__ tmat) {
    __shared__ __align__(16) char smem[43008];
    float (*Ps)[40]  = (float(*)[40])smem;              // 10240 B (z=1 only)
    ushort_t* Vs     = (ushort_t*)(smem + 10240);       // 32768 B (z=1 only)
    const int b = blockIdx.y;
    const int n0 = blockIdx.x * 64;
    const int t = threadIdx.x;
    const int lane = t & 63;
    const int w = t >> 6;           // wave id = M-tile (16 rows each)
    const int quad = lane >> 4;
    const int l16 = lane & 15;
    const ushort_t* __restrict__ A = (blockIdx.z == 0) ? qbf : kbf;
    const ushort_t* __restrict__ Arow = A + ((size_t)b * SEQ + n0 + w * 16 + l16) * 256;
    const ushort_t* __restrict__ Sb = sel + (size_t)b * NLMP * 256 + (size_t)l16 * 256;

    floatx4 acc[3];
#pragma unroll
    for (int ct = 0; ct < 3; ct++) acc[ct] = (floatx4){0.f, 0.f, 0.f, 0.f};

#pragma unroll
    for (int ks = 0; ks < 8; ks++) {
        const int ko = ks * 32 + quad * 8;
        const short8 a  = *(const short8*)&Arow[ko];
        const short8 b0 = *(const short8*)&Sb[ko];
        const short8 b1 = *(const short8*)&Sb[16 * 256 + ko];
        const short8 b2 = *(const short8*)&Sb[32 * 256 + ko];
        acc[0] = __builtin_amdgcn_mfma_f32_16x16x32_bf16(a, b0, acc[0], 0, 0, 0);
        acc[1] = __builtin_amdgcn_mfma_f32_16x16x32_bf16(a, b1, acc[1], 0, 0, 0);
        acc[2] = __builtin_amdgcn_mfma_f32_16x16x32_bf16(a, b2, acc[2], 0, 0, 0);
    }

    // Softmax over 40 landmark cols, per output row (= w*16 + quad*4 + reg).
    const bool v2ok = (l16 < 8);    // ct==2 col = 32+l16 valid iff < 40
    float p0[4], p1[4], p2[4];
#pragma unroll
    for (int reg = 0; reg < 4; reg++) {
        const float l0 = acc[0][reg] * INV_SCALE;
        const float l1 = acc[1][reg] * INV_SCALE;
        const float l2 = acc[2][reg] * INV_SCALE;
        float m = fmaxf(l0, l1);
        if (v2ok) m = fmaxf(m, l2);
        m = fmaxf(m, __shfl_xor(m, 1));
        m = fmaxf(m, __shfl_xor(m, 2));
        m = fmaxf(m, __shfl_xor(m, 4));
        m = fmaxf(m, __shfl_xor(m, 8));
        const float e0 = expf(l0 - m);
        const float e1 = expf(l1 - m);
        const float e2 = v2ok ? expf(l2 - m) : 0.f;
        float s = e0 + e1 + e2;
        s += __shfl_xor(s, 1);
        s += __shfl_xor(s, 2);
        s += __shfl_xor(s, 4);
        s += __shfl_xor(s, 8);
        const float inv = 1.f / s;
        p0[reg] = e0 * inv; p1[reg] = e1 * inv; p2[reg] = e2 * inv;
    }

    const int row0 = w * 16 + quad * 4;
    if (blockIdx.z == 0) {
        float* __restrict__ dst = &simq[((size_t)b * SEQ + n0 + row0) * NLM];
#pragma unroll
        for (int reg = 0; reg < 4; reg++) {
            float* __restrict__ d2 = dst + reg * NLM;
            d2[l16] = p0[reg];
            d2[16 + l16] = p1[reg];
            if (v2ok) d2[32 + l16] = p2[reg];
        }
        return;
    }

    // ---- z=1: probs -> Ps, then tmat accumulation in-place (R11 phase B) ----
#pragma unroll
    for (int reg = 0; reg < 4; reg++) {
        Ps[row0 + reg][l16] = p0[reg];
        Ps[row0 + reg][16 + l16] = p1[reg];
        if (v2ok) Ps[row0 + reg][32 + l16] = p2[reg];
    }
    // V-stage: 8 x 1KB global_load_lds per wave; wave w rows {w*2+u*8 +0..1}
#pragma unroll
    for (int u = 0; u < 8; u++) {
        gload_lds16(&vbf[((size_t)b * SEQ + n0 + w * 2 + u * 8 + (lane >> 5)) * 256 +
                         (lane & 31) * 8],
                    &Vs[(w * 2 + u * 8) * 256]);
    }
    __syncthreads();

    float tac[40];
#pragma unroll
    for (int j = 0; j < 40; j++) tac[j] = 0.f;

#pragma unroll 2
    for (int m = 0; m < 64; m++) {
        const float vv = bf2f(Vs[m * 256 + t]);   // 2-way bank alias: free
#pragma unroll
        for (int j4 = 0; j4 < 10; j4++) {
            const float4 p = *(const float4*)&Ps[m][j4 * 4];  // broadcast
            tac[j4 * 4 + 0] = fmaf(p.x, vv, tac[j4 * 4 + 0]);
            tac[j4 * 4 + 1] = fmaf(p.y, vv, tac[j4 * 4 + 1]);
            tac[j4 * 4 + 2] = fmaf(p.z, vv, tac[j4 * 4 + 2]);
            tac[j4 * 4 + 3] = fmaf(p.w, vv, tac[j4 * 4 + 3]);
        }
    }
#pragma unroll
    for (int j = 0; j < 40; j++)
        atomicAdd(&tmat[(size_t)b * NLM * 256 + j * 256 + t], tac[j]);
}

// ---------------------------------------------------------------------------
// out_fused v4 (R21, kept): grid 512 (32 rows/block), block 512 (8 waves),
// 54 KB LDS -> 2 blocks/CU. OP once per col; Bs via gload_lds16 DMA from
// precomputed wobf. Bit-identical to the R19/R20 out path.
// ---------------------------------------------------------------------------
__global__ __launch_bounds__(512) void out_fused(const float* __restrict__ simq,
                                                 const float* __restrict__ tmat,
                                                 const ushort_t* __restrict__ wobf,
                                                 const float* __restrict__ bias,
                                                 const float* __restrict__ resid,
                                                 float* __restrict__ out) {
    __shared__ __align__(16) char smem[54272];
    float* Ps = (float*)smem;                      // [32*40] fp32   5120 B
    ushort_t* Ac = (ushort_t*)(smem + 5120);       // [32][256] bf16 16384 B
    ushort_t* Bs = (ushort_t*)(smem + 21504);      // [256][64] bf16 32768 B

    const int t = threadIdx.x;
    const int m0 = blockIdx.x * 32;
    const int b = blockIdx.x >> 8;                 // 256 blocks per batch
    const int lane = t & 63;
    const int w = t >> 6;                          // 0..7
    const int quad = lane >> 4;
    const int l16 = lane & 15;
    const int xsw = l16 & 7;
    const int rt_base = (w & 1) * 16;              // wave row tile (0 or 16)
    const int cg_base = (w >> 1) * 4;              // wave col-tile base (x4 of 16)

    // ---- prologue: stage simq tile ----
    for (int f = t; f < 32 * NLM; f += 512)
        Ps[f] = simq[(size_t)m0 * NLM + f];
    __syncthreads();

    // ---- OP once: thread -> col, 16 rows ----
    {
        const int col = t & 255;
        const int r0 = (t >> 8) * 16;
        const float* __restrict__ Tb = tmat + (size_t)b * NLM * 256;
        float tc[40];
#pragma unroll
        for (int l = 0; l < 40; l++) tc[l] = Tb[l * 256 + col];
        const int chunk = col >> 3;
#pragma unroll
        for (int r = 0; r < 16; r++) {
            const int rr = r0 + r;
            float a = 0.f;
#pragma unroll
            for (int j4 = 0; j4 < 10; j4++) {
                const float4 p = *(const float4*)&Ps[rr * 40 + j4 * 4];
                a = fmaf(p.x, tc[j4 * 4 + 0], a);
                a = fmaf(p.y, tc[j4 * 4 + 1], a);
                a = fmaf(p.z, tc[j4 * 4 + 2], a);
                a = fmaf(p.w, tc[j4 * 4 + 3], a);
            }
            const int pch = (chunk & ~7) | ((chunk & 7) ^ (rr & 7));
            Ac[rr * 256 + pch * 8 + (col & 7)] = f2bf(a);
        }
    }

    floatx4 acc[4];
#pragma unroll
    for (int ct = 0; ct < 4; ct++) acc[ct] = (floatx4){0.f, 0.f, 0.f, 0.f};

    for (int kc = 0; kc < 256; kc += 64) {
        // Bs stage: DMA from wobf (bf16), XOR source-swizzle; wave w stages
        // rows (= output cols) w*32..+31 in 4 calls of 8 rows.
#pragma unroll
        for (int q = 0; q < 4; q++) {
            const int r0 = w * 32 + q * 8;
            gload_lds16(&wobf[(size_t)(r0 + (lane >> 3)) * 256 + kc +
                              (((lane & 7) ^ (lane >> 3)) * 8)],
                        &Bs[r0 * 64]);
        }
        __syncthreads();   // drains gload; also orders Ac writes (first iter)
#pragma unroll
        for (int s = 0; s < 2; s++) {
            // A-frag from Ac: row rt_base+l16, phys chunk (kc>>3)+((s*4+quad)^xsw)
            // -> logical chunk (kc>>3)+(s*4+quad) after write-side XOR cancels.
            const short8 a = *(const short8*)&Ac[(rt_base + l16) * 256 +
                                                 ((kc >> 3) + ((s * 4 + quad) ^ xsw)) * 8];
#pragma unroll
            for (int ct = 0; ct < 4; ct++) {
                const short8 bf = *(const short8*)&Bs[((cg_base + ct) * 16 + l16) * 64 +
                                                      (((s * 4 + quad) ^ xsw) * 8)];
                acc[ct] = __builtin_amdgcn_mfma_f32_16x16x32_bf16(a, bf, acc[ct], 0, 0, 0);
            }
        }
        __syncthreads();
    }

    // Epilogue: direct stores from MFMA C-layout. (acc + bias) + resid.
#pragma unroll
    for (int ct = 0; ct < 4; ct++) {
        const int col = (cg_base + ct) * 16 + l16;
        const float bb = bias[col];
#pragma unroll
        for (int reg = 0; reg < 4; reg++) {
            const int row = rt_base + quad * 4 + reg;
            const size_t idx = (size_t)(m0 + row) * 256 + col;
            out[idx] = (acc[ct][reg] + bb) + resid[idx];
        }
    }
}

// ---------------------------------------------------------------------------
// Workspace (~37 MB). 6 dispatches. R23: exact revert to the R21 config
// (gemm_qkv 128x64 grid 2048; R22's 128x128 regressed +13 us). Measured
// history: R20 175.5 / R21 176.7 / R22 189.6.
// ---------------------------------------------------------------------------
extern "C" void kernel_launch(void* const* d_in, const int* in_sizes, int n_in,
                              void* d_out, int out_size, void* d_ws, size_t ws_size,
                              hipStream_t stream) {
    const float* query = (const float*)d_in[0];
    const float* Wq = (const float*)d_in[1];
    const float* bq = (const float*)d_in[2];
    const float* Wk = (const float*)d_in[3];
    const float* bk = (const float*)d_in[4];
    const float* Wv = (const float*)d_in[5];
    const float* bv = (const float*)d_in[6];
    const float* Wo = (const float*)d_in[7];
    const float* bo = (const float*)d_in[8];
    float* out = (float*)d_out;

    char* p = (char*)d_ws;
    float* simq  = (float*)p;            p += (size_t)MROWS * NLM * 4;      // 2.62 MB
    ushort_t* selbf = (ushort_t*)p;      p += (size_t)BATCH * NLMP * 256 * 2;
    float* tmat  = (float*)p;            p += (size_t)BATCH * NLM * 256 * 4;
    float* partial = (float*)p;          p += (size_t)BATCH * NCBLK * 256 * 4; // 512 KB
    float* ws    = (float*)p;            p += (size_t)BATCH * 256 * 4;
    float* score = (float*)p;            p += (size_t)BATCH * SEQ * 4;
    ushort_t* wobf = (ushort_t*)p;       p += (size_t)256 * 256 * 2;        // 128 KB
    ushort_t* qkv = (ushort_t*)p;        p += (size_t)3 * MROWS * 256 * 2;  // 25.2 MB
    ushort_t* xbf = (ushort_t*)p;        p += (size_t)MROWS * 256 * 2;      // 8.39 MB
    ushort_t* qbf = qkv;
    ushort_t* kbf = qkv + (size_t)MROWS * 256;
    ushort_t* vbf = qkv + (size_t)2 * MROWS * 256;

    const dim3 blk(256);

    convert_colsum<<<dim3(SEQ / 32, BATCH), blk, 0, stream>>>(query, xbf, partial);
    ws_kernel<<<dim3(BATCH), dim3(1024), 0, stream>>>(partial, Wq, bq, Wk, Wo, ws, tmat, wobf);

    gemm_qkv_score<<<dim3(2048), blk, 0, stream>>>(
        xbf, Wq, Wk, Wv, bq, bk, bv, qkv, query, ws, score);

    topk_gather<<<dim3(BATCH), dim3(1024), 0, stream>>>(score, kbf, selbf);

    sim_fused<<<dim3(SEQ / 64, BATCH, 2), blk, 0, stream>>>(qbf, kbf, vbf, selbf, simq, tmat);

    out_fused<<<dim3(MROWS / 32), dim3(512), 0, stream>>>(simq, tmat, wobf, bo, query, out);
}

// Round 15
// 175.177 us; speedup vs baseline: 1.0822x; 1.0172x over previous
//
#include <hip/hip_runtime.h>
#include <cstddef>
#include <cstdint>

// Problem constants (match reference)
#define BATCH 2
#define SEQ 8192
#define CH 256
#define NLM 40
#define NLMP 48               // landmark rows padded to 3 MFMA N-tiles
#define MROWS (BATCH * SEQ)   // 16384
#define INV_SCALE 0.0625f     // 1/sqrt(256)
#define NCBLK 256             // convert_colsum blocks per batch (SEQ/32)

typedef unsigned short ushort_t;
typedef __attribute__((ext_vector_type(8))) short short8;    // 8 bf16 (4 VGPRs)
typedef __attribute__((ext_vector_type(4))) float floatx4;   // MFMA acc

// round-to-nearest-even fp32 -> bf16
__device__ __forceinline__ ushort_t f2bf(float f) {
    unsigned int u = __float_as_uint(f);
    u += 0x7FFFu + ((u >> 16) & 1u);
    return (ushort_t)(u >> 16);
}
__device__ __forceinline__ float bf2f(ushort_t u) {
    return __uint_as_float(((unsigned)u) << 16);
}

// async global->LDS, 16B per lane. LDS dest = wave-uniform base + lane*16
// (m104); global src is per-lane. Drained by __syncthreads (vmcnt0 before
// barrier).
__device__ __forceinline__ void gload_lds16(const ushort_t* g, ushort_t* l) {
    __builtin_amdgcn_global_load_lds(
        (const __attribute__((address_space(1))) unsigned int*)g,
        (__attribute__((address_space(3))) unsigned int*)l, 16, 0, 0);
}

// ---------------------------------------------------------------------------
// convert_colsum: xbf = bf16(x); partial[b][blk][c] = sum of 32 rows of col c.
// grid (SEQ/32, B) = 512 blocks, block 256.
// ---------------------------------------------------------------------------
__global__ __launch_bounds__(256) void convert_colsum(const float* __restrict__ x,
                                                      ushort_t* __restrict__ xbf,
                                                      float* __restrict__ partial) {
    __shared__ float red[4][256];
    const int b = blockIdx.y;
    const int r0 = blockIdx.x * 32;
    const int t = threadIdx.x;
    const int c4 = (t & 63) * 4;     // 0..252
    const int rg = t >> 6;           // 0..3
    const float* base = x + ((size_t)b * SEQ + r0) * 256;
    ushort_t* obase = xbf + ((size_t)b * SEQ + r0) * 256;
    float4 s = {0.f, 0.f, 0.f, 0.f};
#pragma unroll
    for (int i = 0; i < 8; i++) {
        const int r = rg + i * 4;    // 0..31
        const float4 a = *(const float4*)&base[(size_t)r * 256 + c4];
        uint2 o;
        o.x = f2bf(a.x) | ((unsigned)f2bf(a.y) << 16);
        o.y = f2bf(a.z) | ((unsigned)f2bf(a.w) << 16);
        *(uint2*)&obase[(size_t)r * 256 + c4] = o;
        s.x += a.x; s.y += a.y; s.z += a.z; s.w += a.w;
    }
    *(float4*)&red[rg][c4] = s;
    __syncthreads();
    const float tot = red[0][t] + red[1][t] + red[2][t] + red[3][t];
    partial[((size_t)b * NCBLK + blockIdx.x) * 256 + t] = tot;
}

// ---------------------------------------------------------------------------
// ws_kernel: ranking vector in fp32. Also zeros tmat (memset folded in).
// grid (B), block 1024. R16 (kept): Wq row-loads hoisted; bit-identical.
// ---------------------------------------------------------------------------
__global__ __launch_bounds__(1024) void ws_kernel(const float* __restrict__ partial,
                                                  const float* __restrict__ Wq,
                                                  const float* __restrict__ bq,
                                                  const float* __restrict__ Wk,
                                                  float* __restrict__ ws,
                                                  float* __restrict__ tmat) {
    const int b = blockIdx.x;
    __shared__ float xs[256];
    __shared__ float qs[256];
    __shared__ float ppart[4][256];
    const int t = threadIdx.x;
    {
        float* tz = tmat + (size_t)b * NLM * 256;
        for (int i = t; i < NLM * 256; i += 1024) tz[i] = 0.f;
    }
    {
        const int c = t & 255, qd = t >> 8;
        const float* pb = partial + ((size_t)b * NCBLK + qd * 64) * 256 + c;
        float a = 0.f;
#pragma unroll 8
        for (int i = 0; i < 64; i++) a += pb[(size_t)i * 256];
        ppart[qd][c] = a;
    }
    __syncthreads();
    if (t < 256) xs[t] = ppart[0][t] + ppart[1][t] + ppart[2][t] + ppart[3][t];
    __syncthreads();
    const int lane = t & 63, w = t >> 6;
    {
        float4 wq[16];
#pragma unroll
        for (int g = 0; g < 16; g++)
            wq[g] = *(const float4*)&Wq[(size_t)(w * 16 + g) * 256 + lane * 4];
        const float4 x4 = *(const float4*)&xs[lane * 4];
#pragma unroll
        for (int g = 0; g < 16; g++) {
            const int o = w * 16 + g;
            float d = wq[g].x * x4.x + wq[g].y * x4.y + wq[g].z * x4.z + wq[g].w * x4.w;
#pragma unroll
            for (int off = 32; off >= 1; off >>= 1) d += __shfl_down(d, off);
            if (lane == 0) qs[o] = d + 8192.0f * bq[o];
        }
    }
    __syncthreads();
    const int c = t & 255, part = t >> 8;
    float a = 0.f;
#pragma unroll 16
    for (int o = part * 64; o < part * 64 + 64; o++)
        a += Wk[(size_t)o * 256 + c] * qs[o];
    ppart[part][c] = a;
    __syncthreads();
    if (t < 256)
        ws[b * 256 + t] = ppart[0][t] + ppart[1][t] + ppart[2][t] + ppart[3][t];
}

// ---------------------------------------------------------------------------
// gemm_qkv_score: grid 2048 linear (logical (4, 128, 4)).
// R18 (kept): T1 XCD-bijective block swizzle. Pure index permutation.
//   z<3: q/k/v projection (R15: BK=64 + global_load_lds + XOR source-swizzle).
//   z=3: score slice — fp32 ranking path.
// ---------------------------------------------------------------------------
__global__ __launch_bounds__(256) void gemm_qkv_score(const ushort_t* __restrict__ xbf,
                                                      const float* __restrict__ Wq,
                                                      const float* __restrict__ Wk,
                                                      const float* __restrict__ Wv,
                                                      const float* __restrict__ bq,
                                                      const float* __restrict__ bk,
                                                      const float* __restrict__ bv,
                                                      ushort_t* __restrict__ qkv,
                                                      const float* __restrict__ query,
                                                      const float* __restrict__ ws,
                                                      float* __restrict__ score) {
    __shared__ __align__(16) char smem[24576];
    ushort_t* As = (ushort_t*)smem;            // [128][64] bf16, 16 KB
    ushort_t* Bs = (ushort_t*)(smem + 16384);  // [64][64]  bf16,  8 KB
    ushort_t* Es = (ushort_t*)smem;            // epilogue [128][72], 18 KB
    // XCD-bijective swizzle (2048 % 8 == 0)
    const int lin = blockIdx.x;
    const int wg = (lin & 7) * 256 + (lin >> 3);
    const int bx = wg & 3;            // o0 index 0..3
    const int by = (wg >> 2) & 127;   // m0 index 0..127
    const int z = wg >> 9;            // 0..3
    const int t = threadIdx.x;
    const int lane = t & 63;
    const int w = t >> 6;

    if (z == 3) {  // score slice (fp32 ranking path)
        const int blk = by * 4 + bx;                      // 0..511
#pragma unroll
        for (int i = 0; i < 8; i++) {
            const int g = blk * 32 + i * 4 + w;           // row 0..16383
            const int b = g >> 13;
            const int m = g & 8191;
            const float4 kv = *(const float4*)&query[(size_t)g * 256 + lane * 4];
            const float4 qs = *(const float4*)&ws[b * 256 + lane * 4];
            float d = kv.x * qs.x + kv.y * qs.y + kv.z * qs.z + kv.w * qs.w;
#pragma unroll
            for (int off = 32; off >= 1; off >>= 1) d += __shfl_down(d, off);
            if (lane == 0) score[(size_t)b * SEQ + m] = d * INV_SCALE;
        }
        return;
    }

    const float* __restrict__ W = (z == 0) ? Wq : (z == 1) ? Wk : Wv;
    const float* __restrict__ bias = (z == 0) ? bq : (z == 1) ? bk : bv;
    ushort_t* __restrict__ out = qkv + (size_t)z * MROWS * 256;
    const int o0 = bx * 64;
    const int m0 = by * 128;
    const int quad = lane >> 4;
    const int l16 = lane & 15;
    const int xsw = l16 & 7;     // frag-read chunk XOR (== row&7 for A and B)

    floatx4 acc[2][4];
#pragma unroll
    for (int rt = 0; rt < 2; rt++)
#pragma unroll
        for (int ct = 0; ct < 4; ct++) acc[rt][ct] = (floatx4){0.f, 0.f, 0.f, 0.f};

    for (int kc = 0; kc < 256; kc += 64) {
        // A: 16 x 1KB global_load_lds; wave w stages its own rows w*32..+31.
#pragma unroll
        for (int q = 0; q < 4; q++) {
            const int r0 = w * 32 + q * 8;
            gload_lds16(&xbf[(size_t)(m0 + r0 + (lane >> 3)) * 256 + kc +
                             (((lane & 7) ^ (lane >> 3)) * 8)],
                        &As[r0 * 64]);
        }
        // B: reg-stage fp32 -> bf16, 2 uint4/thread, XOR-swizzled ds_write
#pragma unroll
        for (int u = 0; u < 2; u++) {
            const int cid = t + u * 256;
            const int row = cid >> 3;        // 0..63
            const int cch = cid & 7;         // source chunk 0..7
            const float* wp = &W[(size_t)(o0 + row) * 256 + kc + cch * 8];
            const float4 a = *(const float4*)wp;
            const float4 c = *(const float4*)(wp + 4);
            uint4 o;
            o.x = f2bf(a.x) | ((unsigned)f2bf(a.y) << 16);
            o.y = f2bf(a.z) | ((unsigned)f2bf(a.w) << 16);
            o.z = f2bf(c.x) | ((unsigned)f2bf(c.y) << 16);
            o.w = f2bf(c.z) | ((unsigned)f2bf(c.w) << 16);
            *(uint4*)&Bs[row * 64 + ((cch ^ (row & 7)) * 8)] = o;
        }
        __syncthreads();
#pragma unroll
        for (int s = 0; s < 2; s++) {
            short8 a[2], bf[4];
#pragma unroll
            for (int rt = 0; rt < 2; rt++)
                a[rt] = *(const short8*)&As[(w * 32 + rt * 16 + l16) * 64 +
                                            (((s * 4 + quad) ^ xsw) * 8)];
#pragma unroll
            for (int ct = 0; ct < 4; ct++)
                bf[ct] = *(const short8*)&Bs[(ct * 16 + l16) * 64 +
                                             (((s * 4 + quad) ^ xsw) * 8)];
#pragma unroll
            for (int rt = 0; rt < 2; rt++)
#pragma unroll
                for (int ct = 0; ct < 4; ct++)
                    acc[rt][ct] = __builtin_amdgcn_mfma_f32_16x16x32_bf16(
                        a[rt], bf[ct], acc[rt][ct], 0, 0, 0);
        }
        __syncthreads();
    }

    // Epilogue: bias + bf16 into Es (stride 72), then coalesced uint4 stores
#pragma unroll
    for (int rt = 0; rt < 2; rt++) {
#pragma unroll
        for (int ct = 0; ct < 4; ct++) {
            const int col = ct * 16 + l16;
            const float bb = bias[o0 + col];
#pragma unroll
            for (int reg = 0; reg < 4; reg++) {
                const int row = w * 32 + rt * 16 + quad * 4 + reg;
                Es[row * 72 + col] = f2bf(acc[rt][ct][reg] + bb);
            }
        }
    }
    __syncthreads();
#pragma unroll
    for (int u = 0; u < 4; u++) {
        const int cid = t + u * 256;            // 0..1023
        const int row = cid >> 3;               // 0..127
        const int off = (cid & 7) * 8;          // 0..56 (ushorts)
        *(uint4*)&out[(size_t)(m0 + row) * 256 + o0 + off] =
            *(const uint4*)&Es[row * 72 + off];
    }
}

// ---------------------------------------------------------------------------
// Top-40 + gather via RADIX-SELECT. grid (B), block 1024.
// R20 (kept): wave-parallel suffix-scan digit selection (identical set).
// R14: sel bf16 (lossless), padded to NLMP=48 rows.
// ---------------------------------------------------------------------------
__global__ __launch_bounds__(1024) void topk_gather(const float* __restrict__ score,
                                                    const ushort_t* __restrict__ kmat,
                                                    ushort_t* __restrict__ sel) {
    const int b = blockIdx.x;
    const int t = threadIdx.x;
    __shared__ unsigned hist[256];
    __shared__ unsigned sPrefix, sMask, sRem, sNeq;
    __shared__ int sNgt;
    __shared__ int top[NLM];
    __shared__ unsigned topkey[NLM];

    unsigned key[8];
#pragma unroll
    for (int j = 0; j < 8; j++) {
        const unsigned u = __float_as_uint(score[(size_t)b * SEQ + t + j * 1024]);
        key[j] = u ^ (unsigned)(((int)u >> 31) | 0x80000000);
    }
    if (t == 0) { sPrefix = 0; sMask = 0; sRem = NLM; sNgt = 0; sNeq = 0; }

    for (int lvl = 0; lvl < 4; lvl++) {
        const int shift = 24 - 8 * lvl;
        if (t < 256) hist[t] = 0;
        __syncthreads();
        const unsigned pfx = sPrefix, msk = sMask;
#pragma unroll
        for (int j = 0; j < 8; j++)
            if (((key[j] ^ pfx) & msk) == 0)
                atomicAdd(&hist[(key[j] >> shift) & 255u], 1u);
        __syncthreads();
        if (t < 64) {  // wave 0 only
            unsigned sfx = hist[t * 4] + hist[t * 4 + 1] + hist[t * 4 + 2] + hist[t * 4 + 3];
#pragma unroll
            for (int off = 1; off < 64; off <<= 1) {
                const unsigned o = __shfl_down(sfx, off);
                if (t + off < 64) sfx += o;
            }
            const unsigned rem = sRem;
            const unsigned long long mk = __ballot(sfx >= rem);
            const int gstar = 63 - __builtin_clzll(mk);
            unsigned S1 = __shfl(sfx, (gstar + 1) & 63);
            if (gstar == 63) S1 = 0u;
            if (t == 0) {
                int d = gstar * 4 + 3;
                unsigned cum = S1;
                for (; d > gstar * 4; d--) { if (cum + hist[d] >= rem) break; cum += hist[d]; }
                sRem = rem - cum;
                sPrefix |= ((unsigned)d) << shift;
                sMask |= 255u << shift;
            }
        }
        __syncthreads();
    }
    const unsigned K40 = sPrefix;
    const unsigned rem = sRem;
    const int ngt = NLM - (int)rem;

#pragma unroll
    for (int j = 0; j < 8; j++) {
        if (key[j] > K40) {
            const int slot = atomicAdd(&sNgt, 1);
            top[slot] = t + j * 1024; topkey[slot] = key[j];
        } else if (key[j] == K40) {
            const unsigned e = atomicAdd(&sNeq, 1u);
            if (e < rem) {
                const int slot = ngt + (int)e;
                top[slot] = t + j * 1024; topkey[slot] = key[j];
            }
        }
    }
    __syncthreads();

    if (t < 64) {
        unsigned long long c = (t < NLM)
            ? ((((unsigned long long)(~topkey[t])) << 32) | (unsigned)top[t])
            : 0xFFFFFFFFFFFFFFFFull;
#pragma unroll
        for (int kk = 2; kk <= 64; kk <<= 1) {
#pragma unroll
            for (int j = kk >> 1; j >= 1; j >>= 1) {
                const unsigned long long o = __shfl_xor(c, j);
                const bool takeMin = ((t & kk) == 0) == ((t & j) == 0);
                const bool less = c < o;
                c = (takeMin == less) ? c : o;
            }
        }
        if (t < NLM) top[t] = (int)(c & 0xFFFFFFFFu);
    }
    __syncthreads();

    for (int f = t; f < NLMP * 256; f += 1024) {
        const int j = f >> 8;
        const int cc = f & 255;
        sel[(size_t)b * NLMP * 256 + f] =
            (j < NLM) ? kmat[((size_t)b * SEQ + top[j]) * 256 + cc] : (ushort_t)0;
    }
}

// ---------------------------------------------------------------------------
// sim_fused: grid (SEQ/64, B, 2), block 256 (4 waves). R15/R17 structure
// (measured-best). Phase A on bf16 MFMA, DIRECT-from-global frags; softmax on
// MFMA C-layout via shfl_xor row-reduce; cols 40..47 masked.
//   z=0: probs -> simq.   z=1: probs -> Ps LDS, V via global_load_lds,
// broadcast-FMA into tac[40], one atomicAdd batch per block.
// ---------------------------------------------------------------------------
__global__ __launch_bounds__(256, 4) void sim_fused(const ushort_t* __restrict__ qbf,
                                                    const ushort_t* __restrict__ kbf,
                                                    const ushort_t* __restrict__ vbf,
                                                    const ushort_t* __restrict__ sel,
                                                    float* __restrict__ simq,
                                                    float* __restrict__ tmat) {
    __shared__ __align__(16) char smem[43008];
    float (*Ps)[40]  = (float(*)[40])smem;              // 10240 B (z=1 only)
    ushort_t* Vs     = (ushort_t*)(smem + 10240);       // 32768 B (z=1 only)
    const int b = blockIdx.y;
    const int n0 = blockIdx.x * 64;
    const int t = threadIdx.x;
    const int lane = t & 63;
    const int w = t >> 6;           // wave id = M-tile (16 rows each)
    const int quad = lane >> 4;
    const int l16 = lane & 15;
    const ushort_t* __restrict__ A = (blockIdx.z == 0) ? qbf : kbf;
    const ushort_t* __restrict__ Arow = A + ((size_t)b * SEQ + n0 + w * 16 + l16) * 256;
    const ushort_t* __restrict__ Sb = sel + (size_t)b * NLMP * 256 + (size_t)l16 * 256;

    floatx4 acc[3];
#pragma unroll
    for (int ct = 0; ct < 3; ct++) acc[ct] = (floatx4){0.f, 0.f, 0.f, 0.f};

#pragma unroll
    for (int ks = 0; ks < 8; ks++) {
        const int ko = ks * 32 + quad * 8;
        const short8 a  = *(const short8*)&Arow[ko];
        const short8 b0 = *(const short8*)&Sb[ko];
        const short8 b1 = *(const short8*)&Sb[16 * 256 + ko];
        const short8 b2 = *(const short8*)&Sb[32 * 256 + ko];
        acc[0] = __builtin_amdgcn_mfma_f32_16x16x32_bf16(a, b0, acc[0], 0, 0, 0);
        acc[1] = __builtin_amdgcn_mfma_f32_16x16x32_bf16(a, b1, acc[1], 0, 0, 0);
        acc[2] = __builtin_amdgcn_mfma_f32_16x16x32_bf16(a, b2, acc[2], 0, 0, 0);
    }

    // Softmax over 40 landmark cols, per output row (= w*16 + quad*4 + reg).
    const bool v2ok = (l16 < 8);    // ct==2 col = 32+l16 valid iff < 40
    float p0[4], p1[4], p2[4];
#pragma unroll
    for (int reg = 0; reg < 4; reg++) {
        const float l0 = acc[0][reg] * INV_SCALE;
        const float l1 = acc[1][reg] * INV_SCALE;
        const float l2 = acc[2][reg] * INV_SCALE;
        float m = fmaxf(l0, l1);
        if (v2ok) m = fmaxf(m, l2);
        m = fmaxf(m, __shfl_xor(m, 1));
        m = fmaxf(m, __shfl_xor(m, 2));
        m = fmaxf(m, __shfl_xor(m, 4));
        m = fmaxf(m, __shfl_xor(m, 8));
        const float e0 = expf(l0 - m);
        const float e1 = expf(l1 - m);
        const float e2 = v2ok ? expf(l2 - m) : 0.f;
        float s = e0 + e1 + e2;
        s += __shfl_xor(s, 1);
        s += __shfl_xor(s, 2);
        s += __shfl_xor(s, 4);
        s += __shfl_xor(s, 8);
        const float inv = 1.f / s;
        p0[reg] = e0 * inv; p1[reg] = e1 * inv; p2[reg] = e2 * inv;
    }

    const int row0 = w * 16 + quad * 4;
    if (blockIdx.z == 0) {
        float* __restrict__ dst = &simq[((size_t)b * SEQ + n0 + row0) * NLM];
#pragma unroll
        for (int reg = 0; reg < 4; reg++) {
            float* __restrict__ d2 = dst + reg * NLM;
            d2[l16] = p0[reg];
            d2[16 + l16] = p1[reg];
            if (v2ok) d2[32 + l16] = p2[reg];
        }
        return;
    }

    // ---- z=1: probs -> Ps, then tmat accumulation in-place (R11 phase B) ----
#pragma unroll
    for (int reg = 0; reg < 4; reg++) {
        Ps[row0 + reg][l16] = p0[reg];
        Ps[row0 + reg][16 + l16] = p1[reg];
        if (v2ok) Ps[row0 + reg][32 + l16] = p2[reg];
    }
    // V-stage: 8 x 1KB global_load_lds per wave; wave w rows {w*2+u*8 +0..1}
#pragma unroll
    for (int u = 0; u < 8; u++) {
        gload_lds16(&vbf[((size_t)b * SEQ + n0 + w * 2 + u * 8 + (lane >> 5)) * 256 +
                         (lane & 31) * 8],
                    &Vs[(w * 2 + u * 8) * 256]);
    }
    __syncthreads();

    float tac[40];
#pragma unroll
    for (int j = 0; j < 40; j++) tac[j] = 0.f;

#pragma unroll 2
    for (int m = 0; m < 64; m++) {
        const float vv = bf2f(Vs[m * 256 + t]);   // 2-way bank alias: free
#pragma unroll
        for (int j4 = 0; j4 < 10; j4++) {
            const float4 p = *(const float4*)&Ps[m][j4 * 4];  // broadcast
            tac[j4 * 4 + 0] = fmaf(p.x, vv, tac[j4 * 4 + 0]);
            tac[j4 * 4 + 1] = fmaf(p.y, vv, tac[j4 * 4 + 1]);
            tac[j4 * 4 + 2] = fmaf(p.z, vv, tac[j4 * 4 + 2]);
            tac[j4 * 4 + 3] = fmaf(p.w, vv, tac[j4 * 4 + 3]);
        }
    }
#pragma unroll
    for (int j = 0; j < 40; j++)
        atomicAdd(&tmat[(size_t)b * NLM * 256 + j * 256 + t], tac[j]);
}

// ---------------------------------------------------------------------------
// out_fused v3 (R20, best-measured 175.5): OP computed ONCE for all 256 cols
// before the K-loop. grid (256), block 512 (8 waves), 74 KB LDS.
// Thread -> fixed col (col = t&255, rows split 32/32): tc[40] loaded once.
// OP -> Ac[64][256] bf16 LDS with per-8-chunk XOR swizzle (read side
// matches). Per-(r,col) fp32 chain = out_pre's exact association.
// ---------------------------------------------------------------------------
__global__ __launch_bounds__(512) void out_fused(const float* __restrict__ simq,
                                                 const float* __restrict__ tmat,
                                                 const float* __restrict__ Wo,
                                                 const float* __restrict__ bias,
                                                 const float* __restrict__ resid,
                                                 float* __restrict__ out) {
    __shared__ __align__(16) char smem[75776];
    float* Ps = (float*)smem;                      // [64*40] fp32  10240 B
    ushort_t* Ac = (ushort_t*)(smem + 10240);      // [64][256] bf16 32768 B
    ushort_t* Bs = (ushort_t*)(smem + 43008);      // [256][64] bf16 32768 B

    const int t = threadIdx.x;
    const int m0 = blockIdx.x * 64;
    const int b = blockIdx.x >> 7;                 // 128 blocks per batch
    const int lane = t & 63;
    const int w = t >> 6;                          // 0..7
    const int quad = lane >> 4;
    const int l16 = lane & 15;
    const int xsw = l16 & 7;
    const int rt_base = (w & 3) * 16;              // wave row tile (0..48)
    const int cg_base = (w >> 2) * 8;              // wave col-tile base (0 or 8)

    // ---- prologue: stage simq tile ----
    for (int f = t; f < 64 * NLM; f += 512)
        Ps[f] = simq[(size_t)m0 * NLM + f];
    __syncthreads();

    // ---- OP once: thread -> col, 32 rows ----
    {
        const int col = t & 255;
        const int r0 = (t >> 8) * 32;
        const float* __restrict__ Tb = tmat + (size_t)b * NLM * 256;
        float tc[40];
#pragma unroll
        for (int l = 0; l < 40; l++) tc[l] = Tb[l * 256 + col];
        const int chunk = col >> 3;
#pragma unroll
        for (int r = 0; r < 32; r++) {
            const int rr = r0 + r;
            float a = 0.f;
#pragma unroll
            for (int j4 = 0; j4 < 10; j4++) {
                const float4 p = *(const float4*)&Ps[rr * 40 + j4 * 4];
                a = fmaf(p.x, tc[j4 * 4 + 0], a);
                a = fmaf(p.y, tc[j4 * 4 + 1], a);
                a = fmaf(p.z, tc[j4 * 4 + 2], a);
                a = fmaf(p.w, tc[j4 * 4 + 3], a);
            }
            const int pch = (chunk & ~7) | ((chunk & 7) ^ (rr & 7));
            Ac[rr * 256 + pch * 8 + (col & 7)] = f2bf(a);
        }
    }

    floatx4 acc[8];
#pragma unroll
    for (int ct = 0; ct < 8; ct++) acc[ct] = (floatx4){0.f, 0.f, 0.f, 0.f};

    for (int kc = 0; kc < 256; kc += 64) {
        // Bs stage: Wo fp32 -> bf16, XOR-swizzled (rows = output cols 0..255)
#pragma unroll
        for (int u = 0; u < 4; u++) {
            const int cid = t + u * 512;     // 0..2047
            const int row = cid >> 3;        // 0..255
            const int cch = cid & 7;
            const float* wp = &Wo[(size_t)row * 256 + kc + cch * 8];
            const float4 a = *(const float4*)wp;
            const float4 c = *(const float4*)(wp + 4);
            uint4 o;
            o.x = f2bf(a.x) | ((unsigned)f2bf(a.y) << 16);
            o.y = f2bf(a.z) | ((unsigned)f2bf(a.w) << 16);
            o.z = f2bf(c.x) | ((unsigned)f2bf(c.y) << 16);
            o.w = f2bf(c.z) | ((unsigned)f2bf(c.w) << 16);
            *(uint4*)&Bs[row * 64 + ((cch ^ (row & 7)) * 8)] = o;
        }
        __syncthreads();   // also orders Ac writes before first MFMA read
#pragma unroll
        for (int s = 0; s < 2; s++) {
            // A-frag from Ac: row rt_base+l16, k-chunk (kc>>3) + ((s*4+quad)^xsw)
            const short8 a = *(const short8*)&Ac[(rt_base + l16) * 256 +
                                                 ((kc >> 3) + ((s * 4 + quad) ^ xsw)) * 8];
#pragma unroll
            for (int ct = 0; ct < 8; ct++) {
                const short8 bf = *(const short8*)&Bs[((cg_base + ct) * 16 + l16) * 64 +
                                                      (((s * 4 + quad) ^ xsw) * 8)];
                acc[ct] = __builtin_amdgcn_mfma_f32_16x16x32_bf16(a, bf, acc[ct], 0, 0, 0);
            }
        }
        __syncthreads();
    }

    // Epilogue: direct stores from MFMA C-layout. (acc + bias) + resid.
#pragma unroll
    for (int ct = 0; ct < 8; ct++) {
        const int col = (cg_base + ct) * 16 + l16;
        const float bb = bias[col];
#pragma unroll
        for (int reg = 0; reg < 4; reg++) {
            const int row = rt_base + quad * 4 + reg;
            const size_t idx = (size_t)(m0 + row) * 256 + col;
            out[idx] = (acc[ct][reg] + bb) + resid[idx];
        }
    }
}

// ---------------------------------------------------------------------------
// Workspace (~37 MB). 6 dispatches. R24: exact restore of the R20 source —
// the session's best-measured configuration (175.5 us). History:
// R20 175.5 / R21 176.7 / R22 189.6 / R23 178.2 (R21-config n=2 ~177.5).
// ---------------------------------------------------------------------------
extern "C" void kernel_launch(void* const* d_in, const int* in_sizes, int n_in,
                              void* d_out, int out_size, void* d_ws, size_t ws_size,
                              hipStream_t stream) {
    const float* query = (const float*)d_in[0];
    const float* Wq = (const float*)d_in[1];
    const float* bq = (const float*)d_in[2];
    const float* Wk = (const float*)d_in[3];
    const float* bk = (const float*)d_in[4];
    const float* Wv = (const float*)d_in[5];
    const float* bv = (const float*)d_in[6];
    const float* Wo = (const float*)d_in[7];
    const float* bo = (const float*)d_in[8];
    float* out = (float*)d_out;

    char* p = (char*)d_ws;
    float* simq  = (float*)p;            p += (size_t)MROWS * NLM * 4;      // 2.62 MB
    ushort_t* selbf = (ushort_t*)p;      p += (size_t)BATCH * NLMP * 256 * 2;
    float* tmat  = (float*)p;            p += (size_t)BATCH * NLM * 256 * 4;
    float* partial = (float*)p;          p += (size_t)BATCH * NCBLK * 256 * 4; // 512 KB
    float* ws    = (float*)p;            p += (size_t)BATCH * 256 * 4;
    float* score = (float*)p;            p += (size_t)BATCH * SEQ * 4;
    ushort_t* qkv = (ushort_t*)p;        p += (size_t)3 * MROWS * 256 * 2;  // 25.2 MB
    ushort_t* xbf = (ushort_t*)p;        p += (size_t)MROWS * 256 * 2;      // 8.39 MB
    ushort_t* qbf = qkv;
    ushort_t* kbf = qkv + (size_t)MROWS * 256;
    ushort_t* vbf = qkv + (size_t)2 * MROWS * 256;

    const dim3 blk(256);

    convert_colsum<<<dim3(SEQ / 32, BATCH), blk, 0, stream>>>(query, xbf, partial);
    ws_kernel<<<dim3(BATCH), dim3(1024), 0, stream>>>(partial, Wq, bq, Wk, ws, tmat);

    gemm_qkv_score<<<dim3(2048), blk, 0, stream>>>(
        xbf, Wq, Wk, Wv, bq, bk, bv, qkv, query, ws, score);

    topk_gather<<<dim3(BATCH), dim3(1024), 0, stream>>>(score, kbf, selbf);

    sim_fused<<<dim3(SEQ / 64, BATCH, 2), blk, 0, stream>>>(qbf, kbf, vbf, selbf, simq, tmat);

    out_fused<<<dim3(MROWS / 64), dim3(512), 0, stream>>>(simq, tmat, Wo, bo, query, out);
}